// Round 20
// baseline (900.968 us; speedup 1.0000x reference)
//
#include <hip/hip_runtime.h>
#include <hip/hip_bf16.h>
#include <cstdint>
#include <cstddef>

#define EPS_  1e-5f
#define NTV_  204800

typedef unsigned short u16;
typedef __attribute__((ext_vector_type(8))) short short8;
typedef __attribute__((ext_vector_type(4))) float f32x4;

__device__ __forceinline__ float bf2f(u16 u) {
  uint32_t x = (uint32_t)u << 16;
  float f;
  __builtin_memcpy(&f, &x, 4);
  return f;
}
__device__ __forceinline__ u16 f2bf(float f) {
  uint32_t x;
  __builtin_memcpy(&x, &f, 4);
  uint32_t r = (x + 0x7FFFu + ((x >> 16) & 1u)) >> 16;
  return (u16)r;
}

__device__ __forceinline__ void gload_lds16(const u16* g, u16* l) {
  __builtin_amdgcn_global_load_lds(
      (const __attribute__((address_space(1))) uint32_t*)g,
      (__attribute__((address_space(3))) uint32_t*)l, 16, 0, 0);
}

// ---------------- weight convert/repack (f32 -> bf16) + bias concat ----------------
__global__ __launch_bounds__(256) void k_cvtw(
    const float* __restrict__ Wa, const float* __restrict__ Wb_,
    const float* __restrict__ dw, const float* __restrict__ rw,
    const float* __restrict__ Wd, const float* __restrict__ bd,
    const float* __restrict__ ba, const float* __restrict__ bb,
    const float* __restrict__ downbi, const float* __restrict__ resbi,
    u16* __restrict__ WB, float* __restrict__ bd2, float* __restrict__ fbias,
    float* __restrict__ cbias)
{
  int i = blockIdx.x * 256 + threadIdx.x;
  if (i < 9216) { WB[i] = f2bf(Wa[i]); return; }
  i -= 9216;
  if (i < 9216) { WB[9216 + i] = f2bf(Wb_[i]); return; }
  i -= 9216;
  if (i < 12288) { WB[18432 + i] = f2bf(dw[i]); return; }
  i -= 12288;
  if (i < 12288) { WB[30720 + i] = f2bf(rw[i]); return; }
  i -= 12288;
  if (i < 36864) {  // Wd [k,o,c] -> [o][k*64+c]  (stored at WB+43008)
    const int o = i / 192, r = i % 192, k = r >> 6, c = r & 63;
    WB[43008 + i] = f2bf(Wd[((size_t)(k * 192 + o)) * 64 + c]);
    return;
  }
  i -= 36864;
  if (i < 192) { bd2[i] = bd[i] + bd[192 + i] + bd[384 + i]; return; }
  i -= 192;
  if (i < 288) { fbias[i] = (i < 144) ? ba[i] : bb[i - 144]; return; }
  i -= 288;
  if (i < 384) {
    const int g = i / 192, o = i % 192;
    cbias[i] = (g == 0) ? downbi[o] : resbi[o];
  }
}

// ---------------- compose Wc[tapg] = W?2[tapg] @ W?1 (f32 in, bf16 out) + btap ----------------
// grid (11, 48): block (tapg, seg) computes outputs [seg*256, seg*256+256)
__global__ __launch_bounds__(256) void k_wcomp(
    const float* __restrict__ W11, const float* __restrict__ W21, const float* __restrict__ W31,
    const float* __restrict__ W12, const float* __restrict__ W22, const float* __restrict__ W32,
    const float* __restrict__ b11, const float* __restrict__ b21, const float* __restrict__ b31,
    u16* __restrict__ WC, float* __restrict__ btap)
{
  const int tapg = blockIdx.x;            // 0..10
  const int seg  = blockIdx.y;            // 0..47
  const float* W1; const float* W2; const float* b1; int tapl, KT;
  if (tapg == 0)      { W1 = W11; W2 = W12; b1 = b11; tapl = 0;        KT = 1; }
  else if (tapg < 4)  { W1 = W21; W2 = W22; b1 = b21; tapl = tapg - 1; KT = 3; }
  else                { W1 = W31; W2 = W32; b1 = b31; tapl = tapg - 4; KT = 7; }
  const int tid = threadIdx.x;
  const int idx = seg * 256 + tid;        // 0..12287
  const int o = idx / 192, c = idx % 192;
  float s = 0.f;
#pragma unroll 4
  for (int m = 0; m < 192; ++m)
    s += W2[((size_t)o * 192 + m) * KT + tapl] * W1[(size_t)m * 192 + c];
  WC[(size_t)tapg * 12288 + idx] = f2bf(s);
  if (seg == 0 && tid < 64) {
    float sb = 0.f;
    for (int m = 0; m < 192; ++m)
      sb += W2[((size_t)tid * 192 + m) * KT + tapl] * b1[m];
    btap[tapg * 64 + tid] = sb;
  }
}

__global__ void k_bfull(const float* __restrict__ btap,
                        const float* __restrict__ b12, const float* __restrict__ b22,
                        const float* __restrict__ b32, float* __restrict__ bfull)
{
  const int tid = threadIdx.x;
  if (tid >= 192) return;
  const int br = tid / 64, o = tid % 64;
  float s = (br == 0) ? b12[o] : ((br == 1) ? b22[o] : b32[o]);
  const int t0 = (br == 0) ? 0 : ((br == 1) ? 1 : 4);
  const int kt = (br == 0) ? 1 : ((br == 1) ? 3 : 7);
  for (int tap = 0; tap < kt; ++tap) s += btap[(t0 + tap) * 64 + o];
  bfull[tid] = s;
}

// ---------------- x [n,64,t*25+v] f32 -> xb [n, v*256+t, 64] bf16 ----------------
__global__ __launch_bounds__(256) void k_xpose(const float* __restrict__ x, u16* __restrict__ xb)
{
  __shared__ u16 xt[256][72];
  const int bx = blockIdx.x;
  const int n = bx / 25, s0 = (bx % 25) * 256;
  const int tid = threadIdx.x;
  for (int l = tid; l < 64 * 64; l += 256) {
    const int c = l >> 6, q = l & 63;
    float4 v = *(const float4*)&x[((size_t)n * 64 + c) * 6400 + s0 + q * 4];
    xt[q * 4 + 0][c] = f2bf(v.x);
    xt[q * 4 + 1][c] = f2bf(v.y);
    xt[q * 4 + 2][c] = f2bf(v.z);
    xt[q * 4 + 3][c] = f2bf(v.w);
  }
  __syncthreads();
  for (int l = tid; l < 256 * 8; l += 256) {
    const int row = l >> 3, seg = l & 7;
    const int s_old = s0 + row;
    const int dv = s_old % 25, dt = s_old / 25;
    *(uint4*)&xb[((size_t)n * 6400 + dv * 256 + dt) * 64 + seg * 8] = *(const uint4*)&xt[row][seg * 8];
  }
}

// ---------------- conv7: tconv12-shape 1x1 conv; 64-row span, direct 128B-line stores ----------------
// in: CL bf16 [n,6400,C]; Wb: [NP*192][C]; outs: NP CL [n,6400,192]
template<int C, int NP, bool STATS>
__global__ __launch_bounds__(256) void k_conv7(
    const u16* __restrict__ in, const u16* __restrict__ Wb,
    const float* __restrict__ bias,
    u16* __restrict__ out0, u16* __restrict__ out1, u16* __restrict__ out2,
    float* __restrict__ stSum, float* __restrict__ stSq)
{
  constexpr int CS = C / 8;
  constexpr int CH = C / 32;
  __shared__ u16 Bt[64 * C];              // 24 KB (C=192) / 8 KB (C=64)

  const int bx = blockIdx.x;
  const int nb = bx / 100;
  const int sb = (bx % 100) * 64;
  const int tid = threadIdx.x;
  const int w = tid >> 6, lane = tid & 63;
  const int lr = lane & 15, lg = lane >> 4;

  constexpr int SB = 64 * CS;             // 1536 (C=192) / 512 (C=64): multiple of 256
#pragma unroll
  for (int base = 0; base < SB; base += 256) {
    const int slot = base + tid;
    const int r = slot / CS, q = slot % CS;
    gload_lds16(&in[((size_t)nb * 6400 + sb + r) * C + ((q ^ (r & 7)) << 3)],
                &Bt[(size_t)(base + w * 64) * 8]);
  }
  __syncthreads();

  for (int p = 0; p < NP; ++p) {
    u16* outp = (p == 0) ? out0 : ((p == 1) ? out1 : out2);
    for (int br = 0; br < 3; ++br) {
      const u16* Ap = Wb + ((size_t)p * 192 + br * 64) * C;
      short8 af[CH];
#pragma unroll
      for (int j = 0; j < CH; ++j)
        af[j] = *(const short8*)&Ap[((size_t)(w * 16 + lr)) * C + j * 32 + lg * 8];

      f32x4 acc[4];
#pragma unroll
      for (int t = 0; t < 4; ++t) {
        acc[t][0] = 0.f; acc[t][1] = 0.f; acc[t][2] = 0.f; acc[t][3] = 0.f;
      }
#pragma unroll
      for (int t = 0; t < 4; ++t) {
        const int rr = t * 16 + lr;
#pragma unroll
        for (int j = 0; j < CH; ++j) {
          short8 bf = *(const short8*)&Bt[((size_t)rr * CS + ((j * 4 + lg) ^ (rr & 7))) * 8];
          acc[t] = __builtin_amdgcn_mfma_f32_16x16x32_bf16(af[j], bf, acc[t], 0, 0, 0);
        }
      }

      const float4 bv4 = *(const float4*)&bias[p * 192 + br * 64 + w * 16 + lg * 4];
      float ssum[4] = {}, ssq[4] = {};
#pragma unroll
      for (int t = 0; t < 4; ++t) {
        union { uint2 u; u16 s[4]; } pk;
#pragma unroll
        for (int r = 0; r < 4; ++r) {
          float vv = acc[t][r] + ((const float*)&bv4)[r];
          if (STATS) { ssum[r] += vv; ssq[r] += vv * vv; }
          pk.s[r] = f2bf(vv);
        }
        // 4 waves of this block tile a full 128-B line per (br,row)
        *(uint2*)&outp[((size_t)nb * 6400 + sb + t * 16 + lr) * 192 +
                       br * 64 + w * 16 + lg * 4] = pk.u;
      }
      if (STATS) {
#pragma unroll
        for (int r = 0; r < 4; ++r) {
          float ss = ssum[r], sq = ssq[r];
#pragma unroll
          for (int m = 1; m < 16; m <<= 1) { ss += __shfl_xor(ss, m); sq += __shfl_xor(sq, m); }
          if (lr == 0) {
            const int og = p * 192 + br * 64 + w * 16 + lg * 4 + r;
            const int slot = bx & 15;
            atomicAdd(&stSum[og * 16 + slot], ss);
            atomicAdd(&stSq[og * 16 + slot], sq);
          }
        }
      }
    }
  }
}

// ---------------- tconv12: composed-weight tconv; NO Ep — direct 128B-line wave stores ----------------
__global__ __launch_bounds__(256) void k_tconv12(
    const u16* __restrict__ g, const u16* __restrict__ WC,
    const float* __restrict__ bfull, const float* __restrict__ btap,
    u16* __restrict__ out, float* __restrict__ stSum, float* __restrict__ stSq,
    const u16* __restrict__ zp)
{
  constexpr int CS = 24, CH = 6;
  __shared__ u16 Bt[70 * 192];            // 26.25 KB — only LDS use

  const int bx = blockIdx.x;
  const int nb = bx / 100;
  const int sb = (bx % 100) * 64;
  const int tbase = sb & 255;
  const int tid = threadIdx.x;
  const int w = tid >> 6, lane = tid & 63;
  const int lr = lane & 15, lg = lane >> 4;

  constexpr int SB = 70 * CS;             // 1680
  for (int base = 0; base < SB; base += 256) {
    const int slot = base + tid;
    if (slot < SB) {
      const int r = slot / CS, q = slot % CS;
      const int t = tbase - 3 + r;
      const u16* src = ((unsigned)t < 256u)
          ? &g[((size_t)nb * 6400 + sb - 3 + r) * 192 + ((q ^ (r & 7)) << 3)]
          : zp;
      gload_lds16(src, &Bt[(size_t)(base + w * 64) * 8]);
    }
  }
  __syncthreads();

  const bool edge = (tbase == 0) || (tbase == 192);

  for (int br = 0; br < 3; ++br) {
    const int KT = (br == 0) ? 1 : ((br == 1) ? 3 : 7);
    const int tb0 = (br == 0) ? 0 : ((br == 1) ? 1 : 4);
    const u16* Wp = WC + (size_t)tb0 * 12288;

    f32x4 acc[4];
#pragma unroll
    for (int t = 0; t < 4; ++t) {
      acc[t][0] = 0.f; acc[t][1] = 0.f; acc[t][2] = 0.f; acc[t][3] = 0.f;
    }
    const int hofs = 3 - KT / 2;
    for (int tap = 0; tap < KT; ++tap) {
      short8 af[CH];
#pragma unroll
      for (int j = 0; j < CH; ++j)
        af[j] = *(const short8*)&Wp[((size_t)(tap * 64 + w * 16 + lr)) * 192 + j * 32 + lg * 8];
#pragma unroll
      for (int t = 0; t < 4; ++t) {
        const int rr = t * 16 + lr + hofs + tap;
#pragma unroll
        for (int j = 0; j < CH; ++j) {
          short8 bf = *(const short8*)&Bt[((size_t)rr * CS + ((j * 4 + lg) ^ (rr & 7))) * 8];
          acc[t] = __builtin_amdgcn_mfma_f32_16x16x32_bf16(af[j], bf, acc[t], 0, 0, 0);
        }
      }
    }

    float bb[4];
    {
      const float4 bv = *(const float4*)&bfull[br * 64 + w * 16 + lg * 4];
      bb[0] = bv.x; bb[1] = bv.y; bb[2] = bv.z; bb[3] = bv.w;
    }
    float ssum[4] = {}, ssq[4] = {};
#pragma unroll
    for (int t = 0; t < 4; ++t) {
      float b4[4] = {bb[0], bb[1], bb[2], bb[3]};
      if (KT > 1 && edge) {
        const int trow = tbase + t * 16 + lr;
        for (int tap = 0; tap < KT; ++tap) {
          const int dt = tap - KT / 2;
          if ((unsigned)(trow + dt) >= 256u) {
            const float4 bv = *(const float4*)&btap[(tb0 + tap) * 64 + w * 16 + lg * 4];
            b4[0] -= bv.x; b4[1] -= bv.y; b4[2] -= bv.z; b4[3] -= bv.w;
          }
        }
      }
      union { uint2 u; u16 s[4]; } pk;
#pragma unroll
      for (int r = 0; r < 4; ++r) {
        float vv = acc[t][r] + b4[r];
        ssum[r] += vv; ssq[r] += vv * vv;
        pk.s[r] = f2bf(vv);
      }
      // direct store: 4 waves of this block tile a full 128-B line per (br,row)
      *(uint2*)&out[((size_t)nb * 6400 + sb + t * 16 + lr) * 192 +
                    br * 64 + w * 16 + lg * 4] = pk.u;
    }
#pragma unroll
    for (int r = 0; r < 4; ++r) {
      float ss = ssum[r], sq = ssq[r];
#pragma unroll
      for (int m = 1; m < 16; m <<= 1) { ss += __shfl_xor(ss, m); sq += __shfl_xor(sq, m); }
      if (lr == 0) {
        const int og = br * 64 + w * 16 + lg * 4 + r;
        const int slot = bx & 15;
        atomicAdd(&stSum[og * 16 + slot], ss);
        atomicAdd(&stSq[og * 16 + slot], sq);
      }
    }
  }
}

// ---------------- fab conv: C=64 -> O=288, CF out [n,288,6400] ----------------
__global__ __launch_bounds__(256) void k_gemm_cf(
    const u16* __restrict__ in, const u16* __restrict__ Wb,
    const float* __restrict__ bias, u16* __restrict__ out)
{
  __shared__ u16 Bt[128 * 64];
  __shared__ u16 At[288 * 64];
  __shared__ u16 SC[48 * 136];

  const int bx = blockIdx.x;
  const int nb = bx / 50;
  const int sb = (bx % 50) * 128;
  const int v = sb >> 8, tbase = sb & 255;
  const int tid = threadIdx.x;
  const int w = tid >> 6, lane = tid & 63;
  const int lr = lane & 15, lg = lane >> 4;
  const int s_w = w * 32;

  for (int base = 0; base < 1024; base += 256) {
    const int slot = base + tid;
    const int r = slot >> 3, q = slot & 7;
    gload_lds16(&in[((size_t)nb * 6400 + v * 256 + tbase + r) * 64 + ((q ^ (r & 7)) << 3)],
                &Bt[(size_t)(base + w * 64) * 8]);
  }
  for (int base = 0; base < 2304; base += 256) {
    const int slot = base + tid;
    const int r = slot >> 3, q = slot & 7;
    gload_lds16(&Wb[(size_t)r * 64 + ((q ^ (r & 7)) << 3)],
                &At[(size_t)(base + w * 64) * 8]);
  }
  __syncthreads();

  for (int p = 0; p < 6; ++p) {
    f32x4 acc[3][2];
#pragma unroll
    for (int mi = 0; mi < 3; ++mi)
#pragma unroll
      for (int ni = 0; ni < 2; ++ni) {
        acc[mi][ni][0] = 0.f; acc[mi][ni][1] = 0.f; acc[mi][ni][2] = 0.f; acc[mi][ni][3] = 0.f;
      }
#pragma unroll
    for (int ch = 0; ch < 2; ++ch) {
      const int j = ch * 4 + lg;
      short8 af[3], bf[2];
#pragma unroll
      for (int mi = 0; mi < 3; ++mi) {
        const int r = p * 48 + mi * 16 + lr;
        af[mi] = *(const short8*)&At[((size_t)r * 8 + (j ^ (r & 7))) * 8];
      }
#pragma unroll
      for (int ni = 0; ni < 2; ++ni) {
        const int r = s_w + ni * 16 + lr;
        bf[ni] = *(const short8*)&Bt[((size_t)r * 8 + (j ^ (r & 7))) * 8];
      }
#pragma unroll
      for (int mi = 0; mi < 3; ++mi)
#pragma unroll
        for (int ni = 0; ni < 2; ++ni)
          acc[mi][ni] = __builtin_amdgcn_mfma_f32_16x16x32_bf16(af[mi], bf[ni], acc[mi][ni], 0, 0, 0);
    }
#pragma unroll
    for (int mi = 0; mi < 3; ++mi)
#pragma unroll
      for (int r = 0; r < 4; ++r) {
        const float bv = bias[p * 48 + mi * 16 + lg * 4 + r];
#pragma unroll
        for (int ni = 0; ni < 2; ++ni) acc[mi][ni][r] += bv;
      }
    __syncthreads();
#pragma unroll
    for (int mi = 0; mi < 3; ++mi)
#pragma unroll
      for (int ni = 0; ni < 2; ++ni)
#pragma unroll
        for (int r = 0; r < 4; ++r)
          SC[(mi * 16 + lg * 4 + r) * 136 + s_w + ni * 16 + lr] = f2bf(acc[mi][ni][r]);
    __syncthreads();
#pragma unroll
    for (int it = 0; it < 3; ++it) {
      const int row = it * 16 + (tid >> 4), chunk = tid & 15;
      *(uint4*)&out[((size_t)nb * 288 + p * 48 + row) * 6400 + sb + chunk * 8] =
          *(const uint4*)&SC[row * 136 + chunk * 8];
    }
  }
}

// ---------------- attention scores partials ----------------
__device__ __forceinline__ float dot4(uint2 a, uint2 b) {
  return bf2f((u16)(a.x & 0xffff)) * bf2f((u16)(b.x & 0xffff)) +
         bf2f((u16)(a.x >> 16))    * bf2f((u16)(b.x >> 16)) +
         bf2f((u16)(a.y & 0xffff)) * bf2f((u16)(b.y & 0xffff)) +
         bf2f((u16)(a.y >> 16))    * bf2f((u16)(b.y >> 16));
}

__global__ __launch_bounds__(256) void k_scores_part(
    const u16* __restrict__ fab, float* __restrict__ part)
{
  const int nk = blockIdx.x;
  const int seg = blockIdx.y;
  const int n = nk / 3, k = nk % 3;
  __shared__ u16 sa[12800], sb[12800];
  const int tid = threadIdx.x;
  const u16* fap = fab + ((size_t)(n * 288 + k * 48 + seg * 2)) * 6400;
  const u16* fbp = fab + ((size_t)(n * 288 + 144 + k * 48 + seg * 2)) * 6400;
  for (int l = tid; l < 1600; l += 256) {
    ((uint4*)sa)[l] = ((const uint4*)fap)[l];
    ((uint4*)sb)[l] = ((const uint4*)fbp)[l];
  }
  __syncthreads();

  const int l0 = tid, l1 = tid + 256, l2 = tid + 512;
  const bool ok2 = (l2 < 625);
  const int v0 = l0 / 25, w0 = l0 % 25;
  const int v1 = l1 / 25, w1 = l1 % 25;
  const int v2 = ok2 ? l2 / 25 : 0, w2 = ok2 ? l2 % 25 : 0;
  float a0 = 0.f, a1 = 0.f, a2 = 0.f;
  const int rot = ((tid & 63) * 4) & 255;

#pragma unroll
  for (int ch = 0; ch < 2; ++ch) {
    const u16* pa = sa + ch * 6400;
    const u16* pb = sb + ch * 6400;
    for (int it = 0; it < 64; ++it) {
      const int t = (it * 4 + rot) & 255;
      a0 += dot4(*(const uint2*)&pa[v0 * 256 + t], *(const uint2*)&pb[w0 * 256 + t]);
      a1 += dot4(*(const uint2*)&pa[v1 * 256 + t], *(const uint2*)&pb[w1 * 256 + t]);
      if (ok2)
        a2 += dot4(*(const uint2*)&pa[v2 * 256 + t], *(const uint2*)&pb[w2 * 256 + t]);
    }
  }
  float* po = part + ((size_t)nk * 24 + seg) * 640;
  po[l0] = a0;
  po[l1] = a1;
  if (ok2) po[l2] = a2;
}

// ---------------- reduce partials + softmax(+A+PA) ----------------
__global__ __launch_bounds__(256) void k_softmax(
    const float* __restrict__ part, const float* __restrict__ A,
    const float* __restrict__ PA, float* __restrict__ att)
{
  const int nk = blockIdx.x;
  const int n = nk / 3, k = nk % 3;
  __shared__ float sc[640];
  const int tid = threadIdx.x;
  const float* pb = part + (size_t)nk * 24 * 640;
  for (int l = tid; l < 625; l += 256) {
    float s = 0.f;
#pragma unroll
    for (int seg = 0; seg < 24; ++seg) s += pb[seg * 640 + l];
    sc[l] = s;
  }
  __syncthreads();
  if (tid < 25) {
    const int w = tid;
    const float scale = 1.f / 12288.f;
    float m = -1e30f;
    for (int v = 0; v < 25; ++v) m = fmaxf(m, sc[v * 25 + w]);
    m *= scale;
    float e[25], sum = 0.f;
#pragma unroll
    for (int v = 0; v < 25; ++v) { e[v] = __expf(sc[v * 25 + w] * scale - m); sum += e[v]; }
    const float inv = 1.f / sum;
    const float* Ak = A + k * 625;
    const float* Pk = PA + k * 625;
    float* ao = att + ((size_t)n * 3 + k) * 625;
#pragma unroll
    for (int v = 0; v < 25; ++v) ao[v * 25 + w] = e[v] * inv + Ak[v * 25 + w] + Pk[v * 25 + w];
  }
}

// ---------------- z[n, w*256+t, k*64+c] = sum_v xb[n, v*256+t, c] * att[n,k,v,w] ----------------
__global__ __launch_bounds__(256) void k_z(
    const u16* __restrict__ xb, const float* __restrict__ att, u16* __restrict__ z)
{
  __shared__ float attl[1950];
  __shared__ u16 xt[12800];
  const int bx = blockIdx.x;
  const int n = bx >> 5, tb = (bx & 31) * 8;
  const int tid = threadIdx.x;

  for (int l = tid; l < 1875; l += 256) {
    const int k = l / 625, vw = l % 625, v = vw / 25, w = vw % 25;
    attl[(k * 25 + v) * 26 + w] = att[((size_t)n * 3 + k) * 625 + vw];
  }
  for (int l = tid; l < 200 * 8; l += 256) {
    const int j = l >> 3, seg = l & 7;
    const int vv = j >> 3, tl = j & 7;
    *(uint4*)&xt[j * 64 + seg * 8] =
        *(const uint4*)&xb[((size_t)n * 6400 + vv * 256 + tb + tl) * 64 + seg * 8];
  }
  __syncthreads();

  for (int it = 0; it < 19; ++it) {
    const int l = tid + it * 256;
    if (l >= 4800) break;
    const int hi = l >> 6, lo = l & 63;
    const int k = hi / 25, w = hi % 25;
    const int tl = lo >> 3, c0 = (lo & 7) * 8;
    float accv[8] = {};
    for (int v = 0; v < 25; ++v) {
      const float aw = attl[(k * 25 + v) * 26 + w];
      union { uint4 u; u16 s[8]; } xv;
      xv.u = *(const uint4*)&xt[(v * 8 + tl) * 64 + c0];
#pragma unroll
      for (int jj = 0; jj < 8; ++jj) accv[jj] += aw * bf2f(xv.s[jj]);
    }
    union { uint4 u; u16 s[8]; } ov;
#pragma unroll
    for (int jj = 0; jj < 8; ++jj) ov.s[jj] = f2bf(accv[jj]);
    *(uint4*)&z[((size_t)n * 6400 + w * 256 + tb + tl) * 192 + k * 64 + c0] = ov.u;
  }
}

// ---------------- BN finalize ----------------
__global__ void k_bnparams(const float* __restrict__ sSum, const float* __restrict__ sSq,
                           const float* __restrict__ gamma, const float* __restrict__ beta,
                           float* __restrict__ a, float* __restrict__ c, int O)
{
  const int o = threadIdx.x + blockIdx.x * blockDim.x;
  if (o >= O) return;
  float sum = 0.f, sq = 0.f;
#pragma unroll
  for (int s = 0; s < 16; ++s) { sum += sSum[o * 16 + s]; sq += sSq[o * 16 + s]; }
  const float mean = sum * (1.f / NTV_);
  const float var = sq * (1.f / NTV_) - mean * mean;
  const float inv = rsqrtf(var + EPS_);
  const float av = gamma[o] * inv;
  a[o] = av;
  c[o] = beta[o] - av * mean;
}

// ---------------- g = relu(bn(ypre) + bn(down)), all CL streaming ----------------
__global__ __launch_bounds__(256) void k_g2(
    const u16* __restrict__ ypre, const u16* __restrict__ down,
    const float* __restrict__ ga, const float* __restrict__ gc,
    const float* __restrict__ da, const float* __restrict__ dc,
    u16* __restrict__ g)
{
  __shared__ float pA1[192], pC1[192], pA2[192], pC2[192];
  const int tid = threadIdx.x;
  if (tid < 192) { pA1[tid] = ga[tid]; pC1[tid] = gc[tid]; pA2[tid] = da[tid]; pC2[tid] = dc[tid]; }
  __syncthreads();
  for (size_t i8 = (size_t)blockIdx.x * 256 + tid; i8 < 4915200; i8 += (size_t)gridDim.x * 256) {
    const int c0 = (int)(i8 % 24) * 8;
    union { uint4 u; u16 s[8]; } yv, dv, ov;
    yv.u = *(const uint4*)&ypre[i8 * 8];
    dv.u = *(const uint4*)&down[i8 * 8];
#pragma unroll
    for (int j = 0; j < 8; ++j) {
      const int c = c0 + j;
      ov.s[j] = f2bf(fmaxf(pA1[c] * bf2f(yv.s[j]) + pC1[c] + pA2[c] * bf2f(dv.s[j]) + pC2[c], 0.f));
    }
    *(uint4*)&g[i8 * 8] = ov.u;
  }
}

// ---------------- out = relu(bn_tcn(tm)+bn_res(res)): CL in -> CF f32 out ----------------
__global__ __launch_bounds__(256) void k_out(
    const u16* __restrict__ tm, const u16* __restrict__ resp,
    const float* __restrict__ ta, const float* __restrict__ tc,
    const float* __restrict__ ra, const float* __restrict__ rc,
    float* __restrict__ out)
{
  __shared__ u16 L[100][200];
  __shared__ float pA1[192], pC1[192], pA2[192], pC2[192];
  const int bx = blockIdx.x;
  const int n = bx >> 6, t0 = (bx & 63) * 4;
  const int tid = threadIdx.x;
  if (tid < 192) { pA1[tid] = ta[tid]; pC1[tid] = tc[tid]; pA2[tid] = ra[tid]; pC2[tid] = rc[tid]; }
  __syncthreads();
  for (int l = tid; l < 2400; l += 256) {
    const int row = l / 24, ch = l % 24;
    const int v = row >> 2, tl = row & 3;
    const size_t src = ((size_t)n * 6400 + v * 256 + t0 + tl) * 192 + ch * 8;
    union { uint4 u; u16 s[8]; } tv, rv;
    tv.u = *(const uint4*)&tm[src];
    rv.u = *(const uint4*)&resp[src];
#pragma unroll
    for (int j = 0; j < 8; ++j) {
      const int c = ch * 8 + j;
      L[row][c] = f2bf(fmaxf(pA1[c] * bf2f(tv.s[j]) + pC1[c] + pA2[c] * bf2f(rv.s[j]) + pC2[c], 0.f));
    }
  }
  __syncthreads();
  for (int j = tid; j < 192 * 25; j += 256) {
    const int o = j / 25, q = j % 25;
    float4 f4;
#pragma unroll
    for (int e = 0; e < 4; ++e) {
      const int idx = q * 4 + e;
      const int tl = idx / 25, v = idx % 25;
      ((float*)&f4)[e] = bf2f(L[v * 4 + tl][o]);
    }
    *(float4*)&out[((size_t)n * 192 + o) * 6400 + t0 * 25 + q * 4] = f4;
  }
}

extern "C" void kernel_launch(void* const* d_in, const int* in_sizes, int n_in,
                              void* d_out, int out_size, void* d_ws, size_t ws_size,
                              hipStream_t stream)
{
  const float* x      = (const float*)d_in[0];
  const float* A      = (const float*)d_in[1];
  const float* PA     = (const float*)d_in[2];
  const float* Wa     = (const float*)d_in[3];
  const float* ba     = (const float*)d_in[4];
  const float* Wb     = (const float*)d_in[5];
  const float* bb     = (const float*)d_in[6];
  const float* Wd     = (const float*)d_in[7];
  const float* bd     = (const float*)d_in[8];
  const float* gcng   = (const float*)d_in[9];
  const float* gcnb   = (const float*)d_in[10];
  const float* downw  = (const float*)d_in[11];
  const float* downbi = (const float*)d_in[12];
  const float* downg  = (const float*)d_in[13];
  const float* downb  = (const float*)d_in[14];
  const float* W11    = (const float*)d_in[15];
  const float* b11    = (const float*)d_in[16];
  const float* W21    = (const float*)d_in[17];
  const float* b21    = (const float*)d_in[18];
  const float* W31    = (const float*)d_in[19];
  const float* b31    = (const float*)d_in[20];
  const float* W12    = (const float*)d_in[21];
  const float* b12    = (const float*)d_in[22];
  const float* W22    = (const float*)d_in[23];
  const float* b22    = (const float*)d_in[24];
  const float* W32    = (const float*)d_in[25];
  const float* b32    = (const float*)d_in[26];
  const float* tcng   = (const float*)d_in[27];
  const float* tcnb   = (const float*)d_in[28];
  const float* resw   = (const float*)d_in[29];
  const float* resbi  = (const float*)d_in[30];
  const float* resg   = (const float*)d_in[31];
  const float* resb   = (const float*)d_in[32];
  (void)in_sizes; (void)n_in; (void)out_size; (void)ws_size;

  // ---- d_out overlay ----
  u16* ob = (u16*)d_out;
  u16* fab   = ob;                             // [32,288,6400] CF (dead after scores)
  u16* xb    = ob + 58982400;                  // [32,6400,64] CL (dead after down/res)
  float* att = (float*)(ob + 72089600);        // dead after k_z
  float* part  = (float*)(ob + 72584768);      // dead after softmax
  float* fbias = (float*)(ob + 75533888);      // dead after fab conv
  u16*   WC    = ob + 75534464;                // [11][64][192] bf16 composed (live till tconv12)
  float* btap  = (float*)(ob + 75669760);      // [11][64] f32
  float* bfull = (float*)(ob + 75671296);      // [3][64] f32

  // ---- ws: 4 big slots + small region ----
  char* ws = (char*)d_ws;
  const size_t SLOT = 78643200;
  u16* z     = (u16*)(ws);             // later g
  u16* g     = (u16*)(ws);
  u16* ypre  = (u16*)(ws + SLOT);
  u16* down  = (u16*)(ws + 2 * SLOT);  // later tm
  u16* tm    = (u16*)(ws + 2 * SLOT);
  u16* resp  = (u16*)(ws + 3 * SLOT);
  char* sm   = ws + 4 * SLOT;
  float* bnp   = (float*)(sm);                 // 1536 f32
  u16*   zp    = (u16*)(sm + 8192);            // 256 B zero page
  u16*   WB    = (u16*)(sm + 8704);            // weights: fab 18432, down/res 24576, Wd 36864
  float* bd2   = (float*)(sm + 660224);        // 192 f32
  float* cbias = (float*)(sm + 661248);        // 384 f32 (down,res biases)
  float* slots = (float*)(sm + 665600);        // 24576 f32
  float* gcnSum = slots;           float* gcnSq = slots + 3072;
  float* dwnSum = slots + 6144;    float* resSum = slots + 9216;
  float* dwnSq  = slots + 12288;   float* resSq  = slots + 15360;
  float* tmSum  = slots + 18432;   float* tmSq   = slots + 21504;
  float* gcnA = bnp;          float* gcnC = bnp + 192;
  float* dwnA = bnp + 384;    float* dwnC = bnp + 576;
  float* resA = bnp + 768;    float* resC = bnp + 960;
  float* tmA  = bnp + 1152;   float* tmC  = bnp + 1344;

  hipMemsetAsync(slots, 0, 24576 * 4, stream);
  hipMemsetAsync(zp, 0, 256, stream);

  const dim3 blk(256);

  k_cvtw<<<dim3(316), blk, 0, stream>>>(Wa, Wb, downw, resw, Wd, bd, ba, bb,
                                        downbi, resbi, WB, bd2, fbias, cbias);
  k_wcomp<<<dim3(11, 48), blk, 0, stream>>>(W11, W21, W31, W12, W22, W32,
                                            b11, b21, b31, WC, btap);
  k_bfull<<<dim3(1), dim3(192), 0, stream>>>(btap, b12, b22, b32, bfull);
  k_xpose<<<dim3(800), blk, 0, stream>>>(x, xb);

  // ---- unit_gcn ----
  k_gemm_cf<<<dim3(1600), blk, 0, stream>>>(xb, WB, fbias, fab);
  k_scores_part<<<dim3(96, 24), blk, 0, stream>>>(fab, part);
  k_softmax<<<dim3(96), blk, 0, stream>>>(part, A, PA, att);
  k_z<<<dim3(1024), blk, 0, stream>>>(xb, att, z);
  k_conv7<192, 1, true><<<dim3(3200), blk, 0, stream>>>(
      z, WB + 43008, bd2, ypre, ypre, ypre, gcnSum, gcnSq);
  k_conv7<64, 2, true><<<dim3(3200), blk, 0, stream>>>(
      xb, WB + 18432, cbias, down, resp, resp, dwnSum, dwnSq);
  k_bnparams<<<dim3(1), dim3(192), 0, stream>>>(gcnSum, gcnSq, gcng, gcnb, gcnA, gcnC, 192);
  k_bnparams<<<dim3(1), dim3(192), 0, stream>>>(dwnSum, dwnSq, downg, downb, dwnA, dwnC, 192);
  k_bnparams<<<dim3(1), dim3(192), 0, stream>>>(resSum, resSq, resg, resb, resA, resC, 192);
  k_g2<<<dim3(2048), blk, 0, stream>>>(ypre, down, gcnA, gcnC, dwnA, dwnC, g);

  // ---- unit_tcn_m: composed-weight temporal conv directly on g ----
  k_tconv12<<<dim3(3200), blk, 0, stream>>>(
      g, WC, bfull, btap, tm, tmSum, tmSq, zp);
  k_bnparams<<<dim3(1), dim3(192), 0, stream>>>(tmSum, tmSq, tcng, tcnb, tmA, tmC, 192);

  // ---- final combine ----
  k_out<<<dim3(2048), blk, 0, stream>>>(tm, resp, tmA, tmC, resA, resC, (float*)d_out);
}

// Round 21
// 755.595 us; speedup vs baseline: 1.1924x; 1.1924x over previous
//
#include <hip/hip_runtime.h>
#include <hip/hip_bf16.h>
#include <cstdint>
#include <cstddef>

#define EPS_  1e-5f
#define NTV_  204800

typedef unsigned short u16;
typedef __attribute__((ext_vector_type(8))) short short8;
typedef __attribute__((ext_vector_type(4))) float f32x4;

__device__ __forceinline__ float bf2f(u16 u) {
  uint32_t x = (uint32_t)u << 16;
  float f;
  __builtin_memcpy(&f, &x, 4);
  return f;
}
__device__ __forceinline__ u16 f2bf(float f) {
  uint32_t x;
  __builtin_memcpy(&x, &f, 4);
  uint32_t r = (x + 0x7FFFu + ((x >> 16) & 1u)) >> 16;
  return (u16)r;
}

__device__ __forceinline__ void gload_lds16(const u16* g, u16* l) {
  __builtin_amdgcn_global_load_lds(
      (const __attribute__((address_space(1))) uint32_t*)g,
      (__attribute__((address_space(3))) uint32_t*)l, 16, 0, 0);
}

// ---------------- weight convert/repack (f32 -> bf16) + bias concat ----------------
__global__ __launch_bounds__(256) void k_cvtw(
    const float* __restrict__ Wa, const float* __restrict__ Wb_,
    const float* __restrict__ dw, const float* __restrict__ rw,
    const float* __restrict__ Wd, const float* __restrict__ bd,
    const float* __restrict__ ba, const float* __restrict__ bb,
    const float* __restrict__ downbi, const float* __restrict__ resbi,
    u16* __restrict__ WB, float* __restrict__ bd2, float* __restrict__ fbias,
    float* __restrict__ cbias)
{
  int i = blockIdx.x * 256 + threadIdx.x;
  if (i < 9216) { WB[i] = f2bf(Wa[i]); return; }
  i -= 9216;
  if (i < 9216) { WB[9216 + i] = f2bf(Wb_[i]); return; }
  i -= 9216;
  if (i < 12288) { WB[18432 + i] = f2bf(dw[i]); return; }
  i -= 12288;
  if (i < 12288) { WB[30720 + i] = f2bf(rw[i]); return; }
  i -= 12288;
  if (i < 36864) {  // Wd [k,o,c] -> [o][k*64+c]  (stored at WB+43008)
    const int o = i / 192, r = i % 192, k = r >> 6, c = r & 63;
    WB[43008 + i] = f2bf(Wd[((size_t)(k * 192 + o)) * 64 + c]);
    return;
  }
  i -= 36864;
  if (i < 192) { bd2[i] = bd[i] + bd[192 + i] + bd[384 + i]; return; }
  i -= 192;
  if (i < 288) { fbias[i] = (i < 144) ? ba[i] : bb[i - 144]; return; }
  i -= 288;
  if (i < 384) {
    const int g = i / 192, o = i % 192;
    cbias[i] = (g == 0) ? downbi[o] : resbi[o];
  }
}

// ---------------- compose Wc[tapg] = W?2[tapg] @ W?1 (f32 in, bf16 out) + btap ----------------
// grid (11, 48): block (tapg, seg) computes outputs [seg*256, seg*256+256)
__global__ __launch_bounds__(256) void k_wcomp(
    const float* __restrict__ W11, const float* __restrict__ W21, const float* __restrict__ W31,
    const float* __restrict__ W12, const float* __restrict__ W22, const float* __restrict__ W32,
    const float* __restrict__ b11, const float* __restrict__ b21, const float* __restrict__ b31,
    u16* __restrict__ WC, float* __restrict__ btap)
{
  const int tapg = blockIdx.x;            // 0..10
  const int seg  = blockIdx.y;            // 0..47
  const float* W1; const float* W2; const float* b1; int tapl, KT;
  if (tapg == 0)      { W1 = W11; W2 = W12; b1 = b11; tapl = 0;        KT = 1; }
  else if (tapg < 4)  { W1 = W21; W2 = W22; b1 = b21; tapl = tapg - 1; KT = 3; }
  else                { W1 = W31; W2 = W32; b1 = b31; tapl = tapg - 4; KT = 7; }
  const int tid = threadIdx.x;
  const int idx = seg * 256 + tid;        // 0..12287
  const int o = idx / 192, c = idx % 192;
  float s = 0.f;
#pragma unroll 4
  for (int m = 0; m < 192; ++m)
    s += W2[((size_t)o * 192 + m) * KT + tapl] * W1[(size_t)m * 192 + c];
  WC[(size_t)tapg * 12288 + idx] = f2bf(s);
  if (seg == 0 && tid < 64) {
    float sb = 0.f;
    for (int m = 0; m < 192; ++m)
      sb += W2[((size_t)tid * 192 + m) * KT + tapl] * b1[m];
    btap[tapg * 64 + tid] = sb;
  }
}

__global__ void k_bfull(const float* __restrict__ btap,
                        const float* __restrict__ b12, const float* __restrict__ b22,
                        const float* __restrict__ b32, float* __restrict__ bfull)
{
  const int tid = threadIdx.x;
  if (tid >= 192) return;
  const int br = tid / 64, o = tid % 64;
  float s = (br == 0) ? b12[o] : ((br == 1) ? b22[o] : b32[o]);
  const int t0 = (br == 0) ? 0 : ((br == 1) ? 1 : 4);
  const int kt = (br == 0) ? 1 : ((br == 1) ? 3 : 7);
  for (int tap = 0; tap < kt; ++tap) s += btap[(t0 + tap) * 64 + o];
  bfull[tid] = s;
}

// ---------------- x [n,64,t*25+v] f32 -> xb [n, v*256+t, 64] bf16 ----------------
__global__ __launch_bounds__(256) void k_xpose(const float* __restrict__ x, u16* __restrict__ xb)
{
  __shared__ u16 xt[256][72];
  const int bx = blockIdx.x;
  const int n = bx / 25, s0 = (bx % 25) * 256;
  const int tid = threadIdx.x;
  for (int l = tid; l < 64 * 64; l += 256) {
    const int c = l >> 6, q = l & 63;
    float4 v = *(const float4*)&x[((size_t)n * 64 + c) * 6400 + s0 + q * 4];
    xt[q * 4 + 0][c] = f2bf(v.x);
    xt[q * 4 + 1][c] = f2bf(v.y);
    xt[q * 4 + 2][c] = f2bf(v.z);
    xt[q * 4 + 3][c] = f2bf(v.w);
  }
  __syncthreads();
  for (int l = tid; l < 256 * 8; l += 256) {
    const int row = l >> 3, seg = l & 7;
    const int s_old = s0 + row;
    const int dv = s_old % 25, dt = s_old / 25;
    *(uint4*)&xb[((size_t)n * 6400 + dv * 256 + dt) * 64 + seg * 8] = *(const uint4*)&xt[row][seg * 8];
  }
}

// ---------------- conv5: 192 thr / 3 waves, wave owns 64 cols, full-line stores ----------------
template<int C, int NP, bool STATS>
__global__ __launch_bounds__(192) void k_conv5(
    const u16* __restrict__ in, const u16* __restrict__ Wb,
    const float* __restrict__ bias,
    u16* __restrict__ out0, u16* __restrict__ out1, u16* __restrict__ out2,
    float* __restrict__ stSum, float* __restrict__ stSq)
{
  constexpr int CS = C / 8;
  constexpr int CH = C / 32;
  constexpr int SB = 128 * CS;
  __shared__ u16 Bt[128 * C];
  __shared__ u16 Ep[3][16 * 72];

  const int bx = blockIdx.x;
  const int nb = bx / 50;
  const int sb = (bx % 50) * 128;
  const int tid = threadIdx.x;
  const int w = tid >> 6, lane = tid & 63;
  const int lr = lane & 15, lg = lane >> 4;

  for (int base = 0; base < SB; base += 192) {
    const int slot = base + tid;
    if ((SB % 192 == 0) || slot < SB) {
      const int r = slot / CS, q = slot % CS;
      gload_lds16(&in[((size_t)nb * 6400 + sb + r) * C + ((q ^ (r & 7)) << 3)],
                  &Bt[(size_t)(base + w * 64) * 8]);
    }
  }
  __syncthreads();

  u16* sc = Ep[w];
  const int o_w = w * 64;
  const int s0 = lane >> 3, seg = lane & 7;

  for (int p = 0; p < NP; ++p) {
    u16* outp = (p == 0) ? out0 : ((p == 1) ? out1 : out2);
    const u16* Ap = Wb + (size_t)p * 192 * C;
    short8 af[4][CH];
#pragma unroll
    for (int mi = 0; mi < 4; ++mi)
#pragma unroll
      for (int j = 0; j < CH; ++j)
        af[mi][j] = *(const short8*)&Ap[((size_t)(o_w + mi * 16 + lr)) * C + j * 32 + lg * 8];
    float4 bv[4];
#pragma unroll
    for (int mi = 0; mi < 4; ++mi)
      bv[mi] = *(const float4*)&bias[p * 192 + o_w + mi * 16 + lg * 4];
    float ssum[4][4] = {}, ssq[4][4] = {};

#pragma unroll
    for (int t = 0; t < 8; ++t) {
      f32x4 acc[4];
#pragma unroll
      for (int mi = 0; mi < 4; ++mi) {
        acc[mi][0] = 0.f; acc[mi][1] = 0.f; acc[mi][2] = 0.f; acc[mi][3] = 0.f;
      }
      const int rr = t * 16 + lr;
#pragma unroll
      for (int j = 0; j < CH; ++j) {
        short8 bf = *(const short8*)&Bt[((size_t)rr * CS + ((j * 4 + lg) ^ (rr & 7))) * 8];
#pragma unroll
        for (int mi = 0; mi < 4; ++mi)
          acc[mi] = __builtin_amdgcn_mfma_f32_16x16x32_bf16(af[mi][j], bf, acc[mi], 0, 0, 0);
      }
#pragma unroll
      for (int mi = 0; mi < 4; ++mi)
#pragma unroll
        for (int r = 0; r < 4; ++r) {
          float vv = acc[mi][r] + ((const float*)&bv[mi])[r];
          if (STATS) { ssum[mi][r] += vv; ssq[mi][r] += vv * vv; }
          sc[lr * 72 + mi * 16 + lg * 4 + r] = f2bf(vv);
        }
#pragma unroll
      for (int pass = 0; pass < 2; ++pass) {
        const int s = pass * 8 + s0;
        uint4 val = *(const uint4*)&sc[s * 72 + seg * 8];
        *(uint4*)&outp[((size_t)nb * 6400 + sb + t * 16 + s) * 192 + o_w + seg * 8] = val;
      }
    }

    if (STATS) {
#pragma unroll
      for (int mi = 0; mi < 4; ++mi)
#pragma unroll
        for (int r = 0; r < 4; ++r) {
          float ss = ssum[mi][r], sq = ssq[mi][r];
#pragma unroll
          for (int m = 1; m < 16; m <<= 1) { ss += __shfl_xor(ss, m); sq += __shfl_xor(sq, m); }
          if (lr == 0) {
            const int og = p * 192 + o_w + mi * 16 + lg * 4 + r;
            const int slot = bx & 15;
            atomicAdd(&stSum[og * 16 + slot], ss);
            atomicAdd(&stSq[og * 16 + slot], sq);
          }
        }
    }
  }
}

// ---------------- tconv12: composed-weight tconv; NO Ep — direct 128B-line wave stores ----------------
__global__ __launch_bounds__(256) void k_tconv12(
    const u16* __restrict__ g, const u16* __restrict__ WC,
    const float* __restrict__ bfull, const float* __restrict__ btap,
    u16* __restrict__ out, float* __restrict__ stSum, float* __restrict__ stSq,
    const u16* __restrict__ zp)
{
  constexpr int CS = 24, CH = 6;
  __shared__ u16 Bt[70 * 192];            // 26.25 KB — only LDS use

  const int bx = blockIdx.x;
  const int nb = bx / 100;
  const int sb = (bx % 100) * 64;
  const int tbase = sb & 255;
  const int tid = threadIdx.x;
  const int w = tid >> 6, lane = tid & 63;
  const int lr = lane & 15, lg = lane >> 4;

  constexpr int SB = 70 * CS;             // 1680
  for (int base = 0; base < SB; base += 256) {
    const int slot = base + tid;
    if (slot < SB) {
      const int r = slot / CS, q = slot % CS;
      const int t = tbase - 3 + r;
      const u16* src = ((unsigned)t < 256u)
          ? &g[((size_t)nb * 6400 + sb - 3 + r) * 192 + ((q ^ (r & 7)) << 3)]
          : zp;
      gload_lds16(src, &Bt[(size_t)(base + w * 64) * 8]);
    }
  }
  __syncthreads();

  const bool edge = (tbase == 0) || (tbase == 192);

  for (int br = 0; br < 3; ++br) {
    const int KT = (br == 0) ? 1 : ((br == 1) ? 3 : 7);
    const int tb0 = (br == 0) ? 0 : ((br == 1) ? 1 : 4);
    const u16* Wp = WC + (size_t)tb0 * 12288;

    f32x4 acc[4];
#pragma unroll
    for (int t = 0; t < 4; ++t) {
      acc[t][0] = 0.f; acc[t][1] = 0.f; acc[t][2] = 0.f; acc[t][3] = 0.f;
    }
    const int hofs = 3 - KT / 2;
    for (int tap = 0; tap < KT; ++tap) {
      short8 af[CH];
#pragma unroll
      for (int j = 0; j < CH; ++j)
        af[j] = *(const short8*)&Wp[((size_t)(tap * 64 + w * 16 + lr)) * 192 + j * 32 + lg * 8];
#pragma unroll
      for (int t = 0; t < 4; ++t) {
        const int rr = t * 16 + lr + hofs + tap;
#pragma unroll
        for (int j = 0; j < CH; ++j) {
          short8 bf = *(const short8*)&Bt[((size_t)rr * CS + ((j * 4 + lg) ^ (rr & 7))) * 8];
          acc[t] = __builtin_amdgcn_mfma_f32_16x16x32_bf16(af[j], bf, acc[t], 0, 0, 0);
        }
      }
    }

    float bb[4];
    {
      const float4 bv = *(const float4*)&bfull[br * 64 + w * 16 + lg * 4];
      bb[0] = bv.x; bb[1] = bv.y; bb[2] = bv.z; bb[3] = bv.w;
    }
    float ssum[4] = {}, ssq[4] = {};
#pragma unroll
    for (int t = 0; t < 4; ++t) {
      float b4[4] = {bb[0], bb[1], bb[2], bb[3]};
      if (KT > 1 && edge) {
        const int trow = tbase + t * 16 + lr;
        for (int tap = 0; tap < KT; ++tap) {
          const int dt = tap - KT / 2;
          if ((unsigned)(trow + dt) >= 256u) {
            const float4 bv = *(const float4*)&btap[(tb0 + tap) * 64 + w * 16 + lg * 4];
            b4[0] -= bv.x; b4[1] -= bv.y; b4[2] -= bv.z; b4[3] -= bv.w;
          }
        }
      }
      union { uint2 u; u16 s[4]; } pk;
#pragma unroll
      for (int r = 0; r < 4; ++r) {
        float vv = acc[t][r] + b4[r];
        ssum[r] += vv; ssq[r] += vv * vv;
        pk.s[r] = f2bf(vv);
      }
      // direct store: 4 waves of this block tile a full 128-B line per (br,row)
      *(uint2*)&out[((size_t)nb * 6400 + sb + t * 16 + lr) * 192 +
                    br * 64 + w * 16 + lg * 4] = pk.u;
    }
#pragma unroll
    for (int r = 0; r < 4; ++r) {
      float ss = ssum[r], sq = ssq[r];
#pragma unroll
      for (int m = 1; m < 16; m <<= 1) { ss += __shfl_xor(ss, m); sq += __shfl_xor(sq, m); }
      if (lr == 0) {
        const int og = br * 64 + w * 16 + lg * 4 + r;
        const int slot = bx & 15;
        atomicAdd(&stSum[og * 16 + slot], ss);
        atomicAdd(&stSq[og * 16 + slot], sq);
      }
    }
  }
}

// ---------------- fab conv: C=64 -> O=288, CF out [n,288,6400] ----------------
__global__ __launch_bounds__(256) void k_gemm_cf(
    const u16* __restrict__ in, const u16* __restrict__ Wb,
    const float* __restrict__ bias, u16* __restrict__ out)
{
  __shared__ u16 Bt[128 * 64];
  __shared__ u16 At[288 * 64];
  __shared__ u16 SC[48 * 136];

  const int bx = blockIdx.x;
  const int nb = bx / 50;
  const int sb = (bx % 50) * 128;
  const int v = sb >> 8, tbase = sb & 255;
  const int tid = threadIdx.x;
  const int w = tid >> 6, lane = tid & 63;
  const int lr = lane & 15, lg = lane >> 4;
  const int s_w = w * 32;

  for (int base = 0; base < 1024; base += 256) {
    const int slot = base + tid;
    const int r = slot >> 3, q = slot & 7;
    gload_lds16(&in[((size_t)nb * 6400 + v * 256 + tbase + r) * 64 + ((q ^ (r & 7)) << 3)],
                &Bt[(size_t)(base + w * 64) * 8]);
  }
  for (int base = 0; base < 2304; base += 256) {
    const int slot = base + tid;
    const int r = slot >> 3, q = slot & 7;
    gload_lds16(&Wb[(size_t)r * 64 + ((q ^ (r & 7)) << 3)],
                &At[(size_t)(base + w * 64) * 8]);
  }
  __syncthreads();

  for (int p = 0; p < 6; ++p) {
    f32x4 acc[3][2];
#pragma unroll
    for (int mi = 0; mi < 3; ++mi)
#pragma unroll
      for (int ni = 0; ni < 2; ++ni) {
        acc[mi][ni][0] = 0.f; acc[mi][ni][1] = 0.f; acc[mi][ni][2] = 0.f; acc[mi][ni][3] = 0.f;
      }
#pragma unroll
    for (int ch = 0; ch < 2; ++ch) {
      const int j = ch * 4 + lg;
      short8 af[3], bf[2];
#pragma unroll
      for (int mi = 0; mi < 3; ++mi) {
        const int r = p * 48 + mi * 16 + lr;
        af[mi] = *(const short8*)&At[((size_t)r * 8 + (j ^ (r & 7))) * 8];
      }
#pragma unroll
      for (int ni = 0; ni < 2; ++ni) {
        const int r = s_w + ni * 16 + lr;
        bf[ni] = *(const short8*)&Bt[((size_t)r * 8 + (j ^ (r & 7))) * 8];
      }
#pragma unroll
      for (int mi = 0; mi < 3; ++mi)
#pragma unroll
        for (int ni = 0; ni < 2; ++ni)
          acc[mi][ni] = __builtin_amdgcn_mfma_f32_16x16x32_bf16(af[mi], bf[ni], acc[mi][ni], 0, 0, 0);
    }
#pragma unroll
    for (int mi = 0; mi < 3; ++mi)
#pragma unroll
      for (int r = 0; r < 4; ++r) {
        const float bv = bias[p * 48 + mi * 16 + lg * 4 + r];
#pragma unroll
        for (int ni = 0; ni < 2; ++ni) acc[mi][ni][r] += bv;
      }
    __syncthreads();
#pragma unroll
    for (int mi = 0; mi < 3; ++mi)
#pragma unroll
      for (int ni = 0; ni < 2; ++ni)
#pragma unroll
        for (int r = 0; r < 4; ++r)
          SC[(mi * 16 + lg * 4 + r) * 136 + s_w + ni * 16 + lr] = f2bf(acc[mi][ni][r]);
    __syncthreads();
#pragma unroll
    for (int it = 0; it < 3; ++it) {
      const int row = it * 16 + (tid >> 4), chunk = tid & 15;
      *(uint4*)&out[((size_t)nb * 288 + p * 48 + row) * 6400 + sb + chunk * 8] =
          *(const uint4*)&SC[row * 136 + chunk * 8];
    }
  }
}

// ---------------- attention scores partials ----------------
__device__ __forceinline__ float dot4(uint2 a, uint2 b) {
  return bf2f((u16)(a.x & 0xffff)) * bf2f((u16)(b.x & 0xffff)) +
         bf2f((u16)(a.x >> 16))    * bf2f((u16)(b.x >> 16)) +
         bf2f((u16)(a.y & 0xffff)) * bf2f((u16)(b.y & 0xffff)) +
         bf2f((u16)(a.y >> 16))    * bf2f((u16)(b.y >> 16));
}

__global__ __launch_bounds__(256) void k_scores_part(
    const u16* __restrict__ fab, float* __restrict__ part)
{
  const int nk = blockIdx.x;
  const int seg = blockIdx.y;
  const int n = nk / 3, k = nk % 3;
  __shared__ u16 sa[12800], sb[12800];
  const int tid = threadIdx.x;
  const u16* fap = fab + ((size_t)(n * 288 + k * 48 + seg * 2)) * 6400;
  const u16* fbp = fab + ((size_t)(n * 288 + 144 + k * 48 + seg * 2)) * 6400;
  for (int l = tid; l < 1600; l += 256) {
    ((uint4*)sa)[l] = ((const uint4*)fap)[l];
    ((uint4*)sb)[l] = ((const uint4*)fbp)[l];
  }
  __syncthreads();

  const int l0 = tid, l1 = tid + 256, l2 = tid + 512;
  const bool ok2 = (l2 < 625);
  const int v0 = l0 / 25, w0 = l0 % 25;
  const int v1 = l1 / 25, w1 = l1 % 25;
  const int v2 = ok2 ? l2 / 25 : 0, w2 = ok2 ? l2 % 25 : 0;
  float a0 = 0.f, a1 = 0.f, a2 = 0.f;
  const int rot = ((tid & 63) * 4) & 255;

#pragma unroll
  for (int ch = 0; ch < 2; ++ch) {
    const u16* pa = sa + ch * 6400;
    const u16* pb = sb + ch * 6400;
    for (int it = 0; it < 64; ++it) {
      const int t = (it * 4 + rot) & 255;
      a0 += dot4(*(const uint2*)&pa[v0 * 256 + t], *(const uint2*)&pb[w0 * 256 + t]);
      a1 += dot4(*(const uint2*)&pa[v1 * 256 + t], *(const uint2*)&pb[w1 * 256 + t]);
      if (ok2)
        a2 += dot4(*(const uint2*)&pa[v2 * 256 + t], *(const uint2*)&pb[w2 * 256 + t]);
    }
  }
  float* po = part + ((size_t)nk * 24 + seg) * 640;
  po[l0] = a0;
  po[l1] = a1;
  if (ok2) po[l2] = a2;
}

// ---------------- reduce partials + softmax(+A+PA) ----------------
__global__ __launch_bounds__(256) void k_softmax(
    const float* __restrict__ part, const float* __restrict__ A,
    const float* __restrict__ PA, float* __restrict__ att)
{
  const int nk = blockIdx.x;
  const int n = nk / 3, k = nk % 3;
  __shared__ float sc[640];
  const int tid = threadIdx.x;
  const float* pb = part + (size_t)nk * 24 * 640;
  for (int l = tid; l < 625; l += 256) {
    float s = 0.f;
#pragma unroll
    for (int seg = 0; seg < 24; ++seg) s += pb[seg * 640 + l];
    sc[l] = s;
  }
  __syncthreads();
  if (tid < 25) {
    const int w = tid;
    const float scale = 1.f / 12288.f;
    float m = -1e30f;
    for (int v = 0; v < 25; ++v) m = fmaxf(m, sc[v * 25 + w]);
    m *= scale;
    float e[25], sum = 0.f;
#pragma unroll
    for (int v = 0; v < 25; ++v) { e[v] = __expf(sc[v * 25 + w] * scale - m); sum += e[v]; }
    const float inv = 1.f / sum;
    const float* Ak = A + k * 625;
    const float* Pk = PA + k * 625;
    float* ao = att + ((size_t)n * 3 + k) * 625;
#pragma unroll
    for (int v = 0; v < 25; ++v) ao[v * 25 + w] = e[v] * inv + Ak[v * 25 + w] + Pk[v * 25 + w];
  }
}

// ---------------- z[n, w*256+t, k*64+c] = sum_v xb[n, v*256+t, c] * att[n,k,v,w] ----------------
__global__ __launch_bounds__(256) void k_z(
    const u16* __restrict__ xb, const float* __restrict__ att, u16* __restrict__ z)
{
  __shared__ float attl[1950];
  __shared__ u16 xt[12800];
  const int bx = blockIdx.x;
  const int n = bx >> 5, tb = (bx & 31) * 8;
  const int tid = threadIdx.x;

  for (int l = tid; l < 1875; l += 256) {
    const int k = l / 625, vw = l % 625, v = vw / 25, w = vw % 25;
    attl[(k * 25 + v) * 26 + w] = att[((size_t)n * 3 + k) * 625 + vw];
  }
  for (int l = tid; l < 200 * 8; l += 256) {
    const int j = l >> 3, seg = l & 7;
    const int vv = j >> 3, tl = j & 7;
    *(uint4*)&xt[j * 64 + seg * 8] =
        *(const uint4*)&xb[((size_t)n * 6400 + vv * 256 + tb + tl) * 64 + seg * 8];
  }
  __syncthreads();

  for (int it = 0; it < 19; ++it) {
    const int l = tid + it * 256;
    if (l >= 4800) break;
    const int hi = l >> 6, lo = l & 63;
    const int k = hi / 25, w = hi % 25;
    const int tl = lo >> 3, c0 = (lo & 7) * 8;
    float accv[8] = {};
    for (int v = 0; v < 25; ++v) {
      const float aw = attl[(k * 25 + v) * 26 + w];
      union { uint4 u; u16 s[8]; } xv;
      xv.u = *(const uint4*)&xt[(v * 8 + tl) * 64 + c0];
#pragma unroll
      for (int jj = 0; jj < 8; ++jj) accv[jj] += aw * bf2f(xv.s[jj]);
    }
    union { uint4 u; u16 s[8]; } ov;
#pragma unroll
    for (int jj = 0; jj < 8; ++jj) ov.s[jj] = f2bf(accv[jj]);
    *(uint4*)&z[((size_t)n * 6400 + w * 256 + tb + tl) * 192 + k * 64 + c0] = ov.u;
  }
}

// ---------------- BN finalize ----------------
__global__ void k_bnparams(const float* __restrict__ sSum, const float* __restrict__ sSq,
                           const float* __restrict__ gamma, const float* __restrict__ beta,
                           float* __restrict__ a, float* __restrict__ c, int O)
{
  const int o = threadIdx.x + blockIdx.x * blockDim.x;
  if (o >= O) return;
  float sum = 0.f, sq = 0.f;
#pragma unroll
  for (int s = 0; s < 16; ++s) { sum += sSum[o * 16 + s]; sq += sSq[o * 16 + s]; }
  const float mean = sum * (1.f / NTV_);
  const float var = sq * (1.f / NTV_) - mean * mean;
  const float inv = rsqrtf(var + EPS_);
  const float av = gamma[o] * inv;
  a[o] = av;
  c[o] = beta[o] - av * mean;
}

// ---------------- g = relu(bn(ypre) + bn(down)), all CL streaming ----------------
__global__ __launch_bounds__(256) void k_g2(
    const u16* __restrict__ ypre, const u16* __restrict__ down,
    const float* __restrict__ ga, const float* __restrict__ gc,
    const float* __restrict__ da, const float* __restrict__ dc,
    u16* __restrict__ g)
{
  __shared__ float pA1[192], pC1[192], pA2[192], pC2[192];
  const int tid = threadIdx.x;
  if (tid < 192) { pA1[tid] = ga[tid]; pC1[tid] = gc[tid]; pA2[tid] = da[tid]; pC2[tid] = dc[tid]; }
  __syncthreads();
  for (size_t i8 = (size_t)blockIdx.x * 256 + tid; i8 < 4915200; i8 += (size_t)gridDim.x * 256) {
    const int c0 = (int)(i8 % 24) * 8;
    union { uint4 u; u16 s[8]; } yv, dv, ov;
    yv.u = *(const uint4*)&ypre[i8 * 8];
    dv.u = *(const uint4*)&down[i8 * 8];
#pragma unroll
    for (int j = 0; j < 8; ++j) {
      const int c = c0 + j;
      ov.s[j] = f2bf(fmaxf(pA1[c] * bf2f(yv.s[j]) + pC1[c] + pA2[c] * bf2f(dv.s[j]) + pC2[c], 0.f));
    }
    *(uint4*)&g[i8 * 8] = ov.u;
  }
}

// ---------------- out = relu(bn_tcn(tm)+bn_res(res)): CL in -> CF f32 out ----------------
__global__ __launch_bounds__(256) void k_out(
    const u16* __restrict__ tm, const u16* __restrict__ resp,
    const float* __restrict__ ta, const float* __restrict__ tc,
    const float* __restrict__ ra, const float* __restrict__ rc,
    float* __restrict__ out)
{
  __shared__ u16 L[100][200];
  __shared__ float pA1[192], pC1[192], pA2[192], pC2[192];
  const int bx = blockIdx.x;
  const int n = bx >> 6, t0 = (bx & 63) * 4;
  const int tid = threadIdx.x;
  if (tid < 192) { pA1[tid] = ta[tid]; pC1[tid] = tc[tid]; pA2[tid] = ra[tid]; pC2[tid] = rc[tid]; }
  __syncthreads();
  for (int l = tid; l < 2400; l += 256) {
    const int row = l / 24, ch = l % 24;
    const int v = row >> 2, tl = row & 3;
    const size_t src = ((size_t)n * 6400 + v * 256 + t0 + tl) * 192 + ch * 8;
    union { uint4 u; u16 s[8]; } tv, rv;
    tv.u = *(const uint4*)&tm[src];
    rv.u = *(const uint4*)&resp[src];
#pragma unroll
    for (int j = 0; j < 8; ++j) {
      const int c = ch * 8 + j;
      L[row][c] = f2bf(fmaxf(pA1[c] * bf2f(tv.s[j]) + pC1[c] + pA2[c] * bf2f(rv.s[j]) + pC2[c], 0.f));
    }
  }
  __syncthreads();
  for (int j = tid; j < 192 * 25; j += 256) {
    const int o = j / 25, q = j % 25;
    float4 f4;
#pragma unroll
    for (int e = 0; e < 4; ++e) {
      const int idx = q * 4 + e;
      const int tl = idx / 25, v = idx % 25;
      ((float*)&f4)[e] = bf2f(L[v * 4 + tl][o]);
    }
    *(float4*)&out[((size_t)n * 192 + o) * 6400 + t0 * 25 + q * 4] = f4;
  }
}

extern "C" void kernel_launch(void* const* d_in, const int* in_sizes, int n_in,
                              void* d_out, int out_size, void* d_ws, size_t ws_size,
                              hipStream_t stream)
{
  const float* x      = (const float*)d_in[0];
  const float* A      = (const float*)d_in[1];
  const float* PA     = (const float*)d_in[2];
  const float* Wa     = (const float*)d_in[3];
  const float* ba     = (const float*)d_in[4];
  const float* Wb     = (const float*)d_in[5];
  const float* bb     = (const float*)d_in[6];
  const float* Wd     = (const float*)d_in[7];
  const float* bd     = (const float*)d_in[8];
  const float* gcng   = (const float*)d_in[9];
  const float* gcnb   = (const float*)d_in[10];
  const float* downw  = (const float*)d_in[11];
  const float* downbi = (const float*)d_in[12];
  const float* downg  = (const float*)d_in[13];
  const float* downb  = (const float*)d_in[14];
  const float* W11    = (const float*)d_in[15];
  const float* b11    = (const float*)d_in[16];
  const float* W21    = (const float*)d_in[17];
  const float* b21    = (const float*)d_in[18];
  const float* W31    = (const float*)d_in[19];
  const float* b31    = (const float*)d_in[20];
  const float* W12    = (const float*)d_in[21];
  const float* b12    = (const float*)d_in[22];
  const float* W22    = (const float*)d_in[23];
  const float* b22    = (const float*)d_in[24];
  const float* W32    = (const float*)d_in[25];
  const float* b32    = (const float*)d_in[26];
  const float* tcng   = (const float*)d_in[27];
  const float* tcnb   = (const float*)d_in[28];
  const float* resw   = (const float*)d_in[29];
  const float* resbi  = (const float*)d_in[30];
  const float* resg   = (const float*)d_in[31];
  const float* resb   = (const float*)d_in[32];
  (void)in_sizes; (void)n_in; (void)out_size; (void)ws_size;

  // ---- d_out overlay ----
  u16* ob = (u16*)d_out;
  u16* fab   = ob;                             // [32,288,6400] CF (dead after scores)
  u16* xb    = ob + 58982400;                  // [32,6400,64] CL (dead after down/res)
  float* att = (float*)(ob + 72089600);        // dead after k_z
  float* part  = (float*)(ob + 72584768);      // dead after softmax
  float* fbias = (float*)(ob + 75533888);      // dead after fab conv
  u16*   WC    = ob + 75534464;                // [11][64][192] bf16 composed (live till tconv12)
  float* btap  = (float*)(ob + 75669760);      // [11][64] f32
  float* bfull = (float*)(ob + 75671296);      // [3][64] f32

  // ---- ws: 4 big slots + small region ----
  char* ws = (char*)d_ws;
  const size_t SLOT = 78643200;
  u16* z     = (u16*)(ws);             // later g
  u16* g     = (u16*)(ws);
  u16* ypre  = (u16*)(ws + SLOT);
  u16* down  = (u16*)(ws + 2 * SLOT);  // later tm
  u16* tm    = (u16*)(ws + 2 * SLOT);
  u16* resp  = (u16*)(ws + 3 * SLOT);
  char* sm   = ws + 4 * SLOT;
  float* bnp   = (float*)(sm);                 // 1536 f32
  u16*   zp    = (u16*)(sm + 8192);            // 256 B zero page
  u16*   WB    = (u16*)(sm + 8704);            // weights: fab 18432, down/res 24576, Wd 36864
  float* bd2   = (float*)(sm + 660224);        // 192 f32
  float* cbias = (float*)(sm + 661248);        // 384 f32 (down,res biases)
  float* slots = (float*)(sm + 665600);        // 24576 f32
  float* gcnSum = slots;           float* gcnSq = slots + 3072;
  float* dwnSum = slots + 6144;    float* resSum = slots + 9216;
  float* dwnSq  = slots + 12288;   float* resSq  = slots + 15360;
  float* tmSum  = slots + 18432;   float* tmSq   = slots + 21504;
  float* gcnA = bnp;          float* gcnC = bnp + 192;
  float* dwnA = bnp + 384;    float* dwnC = bnp + 576;
  float* resA = bnp + 768;    float* resC = bnp + 960;
  float* tmA  = bnp + 1152;   float* tmC  = bnp + 1344;

  hipMemsetAsync(slots, 0, 24576 * 4, stream);
  hipMemsetAsync(zp, 0, 256, stream);

  const dim3 blk(256);
  const dim3 blk3(192);

  k_cvtw<<<dim3(316), blk, 0, stream>>>(Wa, Wb, downw, resw, Wd, bd, ba, bb,
                                        downbi, resbi, WB, bd2, fbias, cbias);
  k_wcomp<<<dim3(11, 48), blk, 0, stream>>>(W11, W21, W31, W12, W22, W32,
                                            b11, b21, b31, WC, btap);
  k_bfull<<<dim3(1), dim3(192), 0, stream>>>(btap, b12, b22, b32, bfull);
  k_xpose<<<dim3(800), blk, 0, stream>>>(x, xb);

  // ---- unit_gcn ----
  k_gemm_cf<<<dim3(1600), blk, 0, stream>>>(xb, WB, fbias, fab);
  k_scores_part<<<dim3(96, 24), blk, 0, stream>>>(fab, part);
  k_softmax<<<dim3(96), blk, 0, stream>>>(part, A, PA, att);
  k_z<<<dim3(1024), blk, 0, stream>>>(xb, att, z);
  k_conv5<192, 1, true><<<dim3(1600), blk3, 0, stream>>>(
      z, WB + 43008, bd2, ypre, ypre, ypre, gcnSum, gcnSq);
  k_conv5<64, 2, true><<<dim3(1600), blk3, 0, stream>>>(
      xb, WB + 18432, cbias, down, resp, resp, dwnSum, dwnSq);
  k_bnparams<<<dim3(1), dim3(192), 0, stream>>>(gcnSum, gcnSq, gcng, gcnb, gcnA, gcnC, 192);
  k_bnparams<<<dim3(1), dim3(192), 0, stream>>>(dwnSum, dwnSq, downg, downb, dwnA, dwnC, 192);
  k_bnparams<<<dim3(1), dim3(192), 0, stream>>>(resSum, resSq, resg, resb, resA, resC, 192);
  k_g2<<<dim3(2048), blk, 0, stream>>>(ypre, down, gcnA, gcnC, dwnA, dwnC, g);

  // ---- unit_tcn_m: composed-weight temporal conv directly on g ----
  k_tconv12<<<dim3(3200), blk, 0, stream>>>(
      g, WC, bfull, btap, tm, tmSum, tmSq, zp);
  k_bnparams<<<dim3(1), dim3(192), 0, stream>>>(tmSum, tmSq, tcng, tcnb, tmA, tmC, 192);

  // ---- final combine ----
  k_out<<<dim3(2048), blk, 0, stream>>>(tm, resp, tmA, tmC, resA, resC, (float*)d_out);
}